// Round 3
// baseline (353.067 us; speedup 1.0000x reference)
//
#include <hip/hip_runtime.h>

#define NN 512
#define CC 1024
#define OO 256
#define VV 68
#define PP 7
#define NC (NN*CC)
#define NV_CNT 34816.0f   // N*T*V = 512*68

typedef float floatx4 __attribute__((ext_vector_type(4)));

__device__ __forceinline__ int part_of(int v){
  return (v>=17)+(v>=22)+(v>=27)+(v>=36)+(v>=42)+(v>=48);
}

// K0: repack w1 [o][c] -> w1p[cb][o] (float4 units), coalesced read.
__global__ __launch_bounds__(256) void k0_prep(const float* __restrict__ w1,
    float* __restrict__ w1p){
  int g = blockIdx.x*256 + threadIdx.x;          // f4 idx in w1: g = o*256+cb
  int o = g >> 8, cb = g & 255;
  float4 v = ((const float4*)w1)[g];
  ((float4*)w1p)[cb*256 + o] = v;
}

// K12: fused part-sum + attention + BN partials. One block per n.
// 512 threads (8 waves) + LDS 64KB -> 2 blocks/CU = 16 waves/CU (4/SIMD),
// 2x the latency hiding of the 256-thread version (which measured 93us at
// Occupancy 20%, VALUBusy 27% -> latency-bound). __launch_bounds__(512,4)
// pins VGPR <=128 so both blocks stay resident.
// Phase A (x8 chunks of 128 c-rows): coalesced f4 load -> LDS transpose
//   stg[v][row] (stride 129) -> per-row part sums; v-space split into 4
//   part-aligned quarters (p0 | p1,p2 | p3,p4 | p5,p6) so each quarter owns
//   COMPLETE parts; S -> GEMM LDS array, sq-sums stay in regs q2r[8][2].
// Phase B: o x c GEMM (w1p from L2, 2-addr LDS broadcasts), softmax.
// Phase C: BN partials; sq combines quarters via LDS strips.
__global__ __launch_bounds__(512, 4) void k12_att(const float* __restrict__ x,
    const float* __restrict__ w1p, const float* __restrict__ b1,
    const float* __restrict__ w2, const float* __restrict__ b2,
    float* __restrict__ att, float* __restrict__ partial){
  int n = blockIdx.x;
  int t = threadIdx.x;

  __shared__ float stg[68*129];                  // 35088 B; reused as hred/sqt
  __shared__ float4 sSf4[PP*256];                // 28672 B: S[p][c] this n
  __shared__ float red_s[4][PP], red_m[4][PP], pre[PP], att_s[PP];
  float* sSl  = (float*)sSf4;                    // [p*1024 + c]
  float* hred = stg;                             // 4096 floats (phase B)
  float* sqt  = stg + 4096;                      // 3*1024 floats (phase C)

  int row  = t & 127;
  int quad = t >> 7;                             // 0..3, wave-pair-uniform

  float q2r[8][2];                               // per-chunk part sq-sums (regs)
  #pragma unroll
  for (int j=0;j<8;j++){ q2r[j][0]=0.f; q2r[j][1]=0.f; }

  const float4* xb = (const float4*)(x + (size_t)n*CC*VV);
  #pragma unroll
  for (int j=0;j<8;j++){
    const float4* src = xb + j*2176;
    #pragma unroll
    for (int k=0;k<5;k++){
      int g = k*512 + t;                         // f4 idx in [0,2176)
      if (k==4 && t>=128) break;
      float4 v4 = src[g];
      int rr = g/17, q = g - rr*17;
      stg[(q*4+0)*129 + rr] = v4.x;
      stg[(q*4+1)*129 + rr] = v4.y;
      stg[(q*4+2)*129 + rr] = v4.z;
      stg[(q*4+3)*129 + rr] = v4.w;
    }
    __syncthreads();
    if (quad==0){                                // p0: v 0..16
      float s0 = 0.f;
      #pragma unroll
      for (int v=0; v<17; v++){
        float e = stg[v*129 + row];
        s0 += e; q2r[j][0] = fmaf(e, e, q2r[j][0]);
      }
      sSl[0*1024 + j*128 + row] = s0;
    } else if (quad==1){                         // p1: 17..21, p2: 22..26
      float s1=0.f, s2=0.f;
      #pragma unroll
      for (int v=17; v<22; v++){
        float e = stg[v*129 + row];
        s1 += e; q2r[j][0] = fmaf(e, e, q2r[j][0]);
      }
      #pragma unroll
      for (int v=22; v<27; v++){
        float e = stg[v*129 + row];
        s2 += e; q2r[j][1] = fmaf(e, e, q2r[j][1]);
      }
      sSl[1*1024 + j*128 + row] = s1;
      sSl[2*1024 + j*128 + row] = s2;
    } else if (quad==2){                         // p3: 27..35, p4: 36..41
      float s3=0.f, s4=0.f;
      #pragma unroll
      for (int v=27; v<36; v++){
        float e = stg[v*129 + row];
        s3 += e; q2r[j][0] = fmaf(e, e, q2r[j][0]);
      }
      #pragma unroll
      for (int v=36; v<42; v++){
        float e = stg[v*129 + row];
        s4 += e; q2r[j][1] = fmaf(e, e, q2r[j][1]);
      }
      sSl[3*1024 + j*128 + row] = s3;
      sSl[4*1024 + j*128 + row] = s4;
    } else {                                     // p5: 42..47, p6: 48..67
      float s5=0.f, s6=0.f;
      #pragma unroll
      for (int v=42; v<48; v++){
        float e = stg[v*129 + row];
        s5 += e; q2r[j][0] = fmaf(e, e, q2r[j][0]);
      }
      #pragma unroll
      for (int v=48; v<68; v++){
        float e = stg[v*129 + row];
        s6 += e; q2r[j][1] = fmaf(e, e, q2r[j][1]);
      }
      sSl[5*1024 + j*128 + row] = s5;
      sSl[6*1024 + j*128 + row] = s6;
    }
    __syncthreads();                             // stg reads done before next stage
  }

  // ---- Phase B: GEMM acc[k][p] = sum_c S[c,p] * w1[o=k*32+oh, c] ----
  int oh = t & 31, ch = t >> 5;                  // ch 0..15
  float acc[8][PP];
  #pragma unroll
  for (int k=0;k<8;k++)
    #pragma unroll
    for (int p=0;p<PP;p++) acc[k][p] = 0.f;

  const float4* wp = (const float4*)w1p;
  #pragma unroll 2
  for (int i=0;i<16;i++){
    int gcb = ch*16 + i;
    const float4* wrow = wp + (size_t)gcb*256 + oh;
    float4 w[8];
    #pragma unroll
    for (int k=0;k<8;k++) w[k] = wrow[32*k];
    #pragma unroll
    for (int p=0;p<PP;p++){
      float4 sv = sSf4[p*256 + gcb];             // 2 addrs/wave broadcast
      #pragma unroll
      for (int k=0;k<8;k++){
        acc[k][p] = fmaf(w[k].x, sv.x, acc[k][p]);
        acc[k][p] = fmaf(w[k].y, sv.y, acc[k][p]);
        acc[k][p] = fmaf(w[k].z, sv.z, acc[k][p]);
        acc[k][p] = fmaf(w[k].w, sv.w, acc[k][p]);
      }
    }
  }

  // reduce over ch (16 groups), mean/max over o, softmax over p
  const float inv_cnt[PP] = {1.f/17.f,1.f/5.f,1.f/5.f,1.f/9.f,1.f/6.f,1.f/6.f,1.f/20.f};
  float bo = (t < OO) ? b1[t] : 0.f;
  float h[PP];
  #pragma unroll
  for (int p=0;p<PP;p++){
    __syncthreads();
    #pragma unroll
    for (int k=0;k<8;k++) hred[ch*256 + k*32 + oh] = acc[k][p];
    __syncthreads();
    if (t < OO){
      float hs = 0.f;
      #pragma unroll
      for (int c16=0;c16<16;c16++) hs += hred[c16*256 + t];
      h[p] = fmaf(hs, inv_cnt[p], bo);
    }
  }

  int lane = t & 63, wid = t >> 6;
  if (t < OO){
    #pragma unroll
    for (int p=0;p<PP;p++){
      float sm = h[p], mx = h[p];
      #pragma unroll
      for (int off=32; off>0; off>>=1){
        sm += __shfl_down(sm, off, 64);
        mx = fmaxf(mx, __shfl_down(mx, off, 64));
      }
      if (lane==0){ red_s[wid][p]=sm; red_m[wid][p]=mx; }
    }
  }
  __syncthreads();
  if (t < PP){
    int p = t;
    float sm = red_s[0][p]+red_s[1][p]+red_s[2][p]+red_s[3][p];
    float mx = fmaxf(fmaxf(red_m[0][p],red_m[1][p]),
                     fmaxf(red_m[2][p],red_m[3][p]));
    pre[p] = w2[0]*(sm*(1.f/(float)OO)) + w2[1]*mx + b2[0];
  }
  __syncthreads();
  if (t == 0){
    float m = pre[0];
    #pragma unroll
    for (int p=1;p<PP;p++) m = fmaxf(m, pre[p]);
    float e[PP], sum=0.f;
    #pragma unroll
    for (int p=0;p<PP;p++){ e[p] = expf(pre[p]-m); sum += e[p]; }
    float inv = 1.f/sum;
    #pragma unroll
    for (int p=0;p<PP;p++){
      float a = e[p]*inv;
      att_s[p] = a;
      att[n*PP+p] = a;
    }
  }
  __syncthreads();

  // ---- Phase C: BN partials ----
  float a[PP];
  #pragma unroll
  for (int p=0;p<PP;p++) a[p] = att_s[p];

  // sm partials: all 512 threads, from LDS S
  #pragma unroll
  for (int jj=0;jj<2;jj++){
    int c = jj*512 + t;
    float sm = 0.f;
    #pragma unroll
    for (int p=0;p<PP;p++) sm = fmaf(a[p], sSl[p*1024 + c], sm);
    partial[n*2048 + c] = sm;
  }

  // sq partials: quarters 1..3 write weighted strips, quarter 0 combines
  if (quad>0){
    int pA = (quad==1)?1:(quad==2)?3:5;
    int pB = pA + 1;
    float aA = a[pA]*a[pA], aB = a[pB]*a[pB];
    #pragma unroll
    for (int j=0;j<8;j++){
      sqt[(quad-1)*1024 + j*128 + row] = aA*q2r[j][0] + aB*q2r[j][1];
    }
  }
  __syncthreads();
  if (quad==0){
    float a0 = a[0]*a[0];
    #pragma unroll
    for (int j=0;j<8;j++){
      int c = j*128 + row;
      float sq = a0*q2r[j][0]
               + sqt[0*1024 + c] + sqt[1*1024 + c] + sqt[2*1024 + c];
      partial[n*2048 + 1024 + c] = sq;
    }
  }
}

// K3b: single-dispatch reduce over n + BN finalize. 32 blocks x 256 thr.
__global__ __launch_bounds__(256) void k3b_finalize(const float* __restrict__ partial,
    const float* __restrict__ gamma, const float* __restrict__ beta,
    float* __restrict__ scsh){
  __shared__ float rs[8][32], rq[8][32];
  int cl = threadIdx.x & 31, grp = threadIdx.x >> 5;
  int c = blockIdx.x*32 + cl;
  float sm=0.f, sq=0.f;
  for (int i=0;i<64;i++){
    int n = grp*64 + i;
    sm += partial[n*2048 + c];
    sq += partial[n*2048 + 1024 + c];
  }
  rs[grp][cl] = sm; rq[grp][cl] = sq;
  __syncthreads();
  if (threadIdx.x < 32){
    float tsm=0.f, tsq=0.f;
    #pragma unroll
    for (int g=0; g<8; g++){ tsm += rs[g][threadIdx.x]; tsq += rq[g][threadIdx.x]; }
    int cc = blockIdx.x*32 + threadIdx.x;
    float mean = tsm * (1.0f/NV_CNT);
    float var  = tsq * (1.0f/NV_CNT) - mean*mean;
    float rstd = rsqrtf(var + 1e-5f);
    float sc = gamma[cc]*rstd;
    scsh[cc]        = sc;
    scsh[1024 + cc] = beta[cc] - mean*sc;
  }
}

// K4: out = relu( x*(att_j*sc + 1) + sh ); nontemporal stores via ext_vector.
__global__ __launch_bounds__(256) void k4_out(const float* __restrict__ x,
    const float* __restrict__ att, const float* __restrict__ scsh,
    float* __restrict__ out){
  int f = blockIdx.x*256 + threadIdx.x;          // float4 index, < NC*17
  int n = blockIdx.x / 68;                       // uniform within block
  __shared__ float s_att[PP];
  if (threadIdx.x < PP) s_att[threadIdx.x] = att[n*PP + threadIdx.x];
  __syncthreads();
  int r = f/17;
  int q = f - r*17;
  int v0 = q*4;
  int c = r & (CC-1);
  float4 xv = ((const float4*)x)[f];
  float sc = scsh[c];
  float sh = scsh[1024 + c];
  float vals[4];
  #pragma unroll
  for (int j=0;j<4;j++){
    int p = part_of(v0 + j);
    float a = s_att[p];
    float e = (j==0)?xv.x:(j==1)?xv.y:(j==2)?xv.z:xv.w;
    vals[j] = fmaxf(fmaf(e, fmaf(a, sc, 1.0f), sh), 0.0f);
  }
  floatx4 ov; ov.x=vals[0]; ov.y=vals[1]; ov.z=vals[2]; ov.w=vals[3];
  __builtin_nontemporal_store(ov, ((floatx4*)out) + f);
}

extern "C" void kernel_launch(void* const* d_in, const int* in_sizes, int n_in,
                              void* d_out, int out_size, void* d_ws, size_t ws_size,
                              hipStream_t stream) {
  const float* x     = (const float*)d_in[0];
  const float* w1    = (const float*)d_in[1];
  const float* b1    = (const float*)d_in[2];
  const float* w2    = (const float*)d_in[3];
  const float* b2    = (const float*)d_in[4];
  const float* gamma = (const float*)d_in[5];
  const float* beta  = (const float*)d_in[6];
  float* out = (float*)d_out;

  float* w1p     = (float*)d_ws;                 // 256*1024 (1 MB)
  float* partial = w1p + OO*CC;                  // 512*2048 (4 MB)
  float* scsh    = partial + NN*2048;            // 2048
  float* att     = scsh + 2048;                  // 512*7
  // ~5 MB of ws; every buffer fully overwritten each call

  k0_prep     <<<256,         256, 0, stream>>>(w1, w1p);
  k12_att     <<<NN,          512, 0, stream>>>(x, w1p, b1, w2, b2, att, partial);
  k3b_finalize<<<32,          256, 0, stream>>>(partial, gamma, beta, scsh);
  k4_out      <<<(NC*17)/256, 256, 0, stream>>>(x, att, scsh, out);
}